// Round 10
// baseline (622.140 us; speedup 1.0000x reference)
//
#include <hip/hip_runtime.h>

// GraphSAGE forward — round 10: r9 champion (bucketed CSR build + fused level
// kernels) with ONLY the wave-private GEMM phases replaced by vector-weight
// register tiling (1 ds_read_b64/b128 weight + 1 broadcast m-read -> VEC
// fmacs per k). Gather geometry byte-identical to r9 (57.4µs, FETCH 80MB).
//
// Hard-won invariants:
//  - Gather reads ONE full contiguous row per vmem instruction, indices
//    shfl-broadcast (r3/r4 fragmentation: FETCH 199-636MB).
//  - Gather stays fused with level GEMMs at moderate occupancy (r7 split
//    doubled HBM traffic).
//  - Scattered 4B writes cost a 64B line each (r8 k_scatter 54MB) -> bucketed
//    two-pass CSR build (r9, proven).
//  - mean_agg(h)@W == mean_agg(h@W): Wa4 folded via k_fold (proven r5-r9).
//  - lvl3 LDS stays exactly 40960B (4 blocks/CU); slot strides chosen so all
//    LDS reads are <=2-way bank aliased (free per m136).

#define BSHIFT 9
#define MAXBUCK 256

__global__ __launch_bounds__(256) void k_count(const int* __restrict__ edst,
                                               int* __restrict__ deg, int E) {
    int t = blockIdx.x * blockDim.x + threadIdx.x;
    if (t < E) atomicAdd(&deg[edst[t]], 1);
}

__global__ __launch_bounds__(256) void k_blocksum(const int* __restrict__ deg,
                                                  int* __restrict__ bsums, int N) {
    __shared__ int s[256];
    int t = threadIdx.x;
    int base = blockIdx.x * 1024 + t * 4;
    int v = 0;
#pragma unroll
    for (int j = 0; j < 4; j++) { int idx = base + j; if (idx < N) v += deg[idx]; }
    s[t] = v; __syncthreads();
    for (int o = 128; o > 0; o >>= 1) { if (t < o) s[t] += s[t + o]; __syncthreads(); }
    if (t == 0) bsums[blockIdx.x] = s[0];
}

__global__ __launch_bounds__(256) void k_scantop(int* __restrict__ bsums, int NB) {
    __shared__ int s[256];
    int t = threadIdx.x;
    int v = (t < NB) ? bsums[t] : 0;
    s[t] = v; __syncthreads();
    for (int o = 1; o < 256; o <<= 1) {
        int x = (t >= o) ? s[t - o] : 0;
        __syncthreads();
        s[t] += x;
        __syncthreads();
    }
    if (t < NB) bsums[t] = s[t] - v;
}

__global__ __launch_bounds__(256) void k_scanfinal(const int* __restrict__ deg,
                                                   const int* __restrict__ bsums,
                                                   int* __restrict__ offsets,
                                                   float* __restrict__ inv_cnt,
                                                   int N, int E) {
    __shared__ int s[256];
    int t = threadIdx.x, b = blockIdx.x;
    int base = b * 1024 + t * 4;
    int d[4]; int lsum = 0;
#pragma unroll
    for (int j = 0; j < 4; j++) { int idx = base + j; d[j] = (idx < N) ? deg[idx] : 0; lsum += d[j]; }
    s[t] = lsum; __syncthreads();
    for (int o = 1; o < 256; o <<= 1) {
        int x = (t >= o) ? s[t - o] : 0;
        __syncthreads();
        s[t] += x;
        __syncthreads();
    }
    int p = bsums[b] + s[t] - lsum;
#pragma unroll
    for (int j = 0; j < 4; j++) {
        int idx = base + j;
        if (idx < N) {
            offsets[idx] = p;
            inv_cnt[idx] = 1.0f / (float)(d[j] > 0 ? d[j] : 1);
            p += d[j];
        }
    }
    if (b == 0 && t == 0) offsets[N] = E;
}

__global__ __launch_bounds__(256) void k_binit(const int* __restrict__ offsets,
                                               int* __restrict__ bcur, int nbuck, int N) {
    int b = blockIdx.x * blockDim.x + threadIdx.x;
    if (b < nbuck) {
        int node = b << BSHIFT;
        bcur[b] = offsets[node < N ? node : N];
    }
}

__global__ __launch_bounds__(512) void k_bucket(const int* __restrict__ esrc,
                                                const int* __restrict__ edst,
                                                int* __restrict__ bcur,
                                                int2* __restrict__ staging,
                                                int nbuck, int E) {
    __shared__ int hist[MAXBUCK];
    __shared__ int bbase[MAXBUCK];
    const int t = threadIdx.x;
    const int e = blockIdx.x * 512 + t;
    int src = 0, dst = 0, b = 0;
    if (e < E) { src = esrc[e]; dst = edst[e]; b = dst >> BSHIFT; }
    for (int i = t; i < nbuck; i += 512) hist[i] = 0;
    __syncthreads();
    int rank = 0;
    if (e < E) rank = atomicAdd(&hist[b], 1);
    __syncthreads();
    for (int i = t; i < nbuck; i += 512)
        bbase[i] = hist[i] ? atomicAdd(&bcur[i], hist[i]) : 0;
    __syncthreads();
    if (e < E) staging[bbase[b] + rank] = make_int2(src, dst);
}

__global__ __launch_bounds__(512) void k_place(const int2* __restrict__ staging,
                                               const int* __restrict__ offsets,
                                               int* __restrict__ csr, int N, int E) {
    __shared__ int cur[1 << BSHIFT];
    const int t = threadIdx.x;
    const int nbase = blockIdx.x << BSHIFT;
    const int nend = min(nbase + (1 << BSHIFT), N);
    for (int i = t; i < nend - nbase; i += 512) cur[i] = offsets[nbase + i];
    __syncthreads();
    const int estart = offsets[nbase], eend = offsets[nend];
    for (int e = estart + t; e < eend; e += 512) {
        int2 pr = staging[e];
        int pos = atomicAdd(&cur[pr.y - nbase], 1);
        csr[pos] = pr.x;
    }
}

// ---- wave-private vector-weight GEMM phases (no barriers; full wave) ----
// out(sl, VEC*q+o) = relu?(sum_k in(sl,k) * W[k][VEC*q+o])
template <int NPG, int K, int KP, int DC, int PADO, int VEC, bool RIN>
__device__ __forceinline__ void wave_mm_lds(const float* wIn, const float* sW,
                                            float* wOut, int lane) {
    constexpr int CQ = DC / VEC;
    constexpr int ITER = (NPG * CQ) / 64;
    static_assert(NPG * CQ == ITER * 64, "tiling mismatch");
#pragma unroll
    for (int r = 0; r < ITER; ++r) {
        int tile = r * 64 + lane;
        int sl = tile / CQ, q = tile % CQ;
        float acc[VEC] = {};
#pragma unroll
        for (int k = 0; k < K; ++k) {
            float w[VEC];
            if constexpr (VEC == 4) *(float4*)w = *(const float4*)&sW[k * DC + 4 * q];
            else                    *(float2*)w = *(const float2*)&sW[k * DC + 2 * q];
            float mv = wIn[sl * KP + k];
            if constexpr (RIN) mv = fmaxf(mv, 0.f);
#pragma unroll
            for (int o = 0; o < VEC; ++o) acc[o] += mv * w[o];
        }
        float rr[VEC];
#pragma unroll
        for (int o = 0; o < VEC; ++o) rr[o] = fmaxf(acc[o], 0.f);
        if constexpr (VEC == 4) *(float4*)&wOut[sl * PADO + 4 * q] = *(float4*)rr;
        else                    *(float2*)&wOut[sl * PADO + 2 * q] = *(float2*)rr;
    }
}

template <int NPG, int K, int KP, int DC, int VEC, bool RIN>
__device__ __forceinline__ void wave_mm_gout(const float* wIn, const float* sW,
                                             float* __restrict__ dst, int nodebase,
                                             int N, int lane) {
    constexpr int CQ = DC / VEC;
    constexpr int ITER = (NPG * CQ) / 64;
    static_assert(NPG * CQ == ITER * 64, "tiling mismatch");
#pragma unroll
    for (int r = 0; r < ITER; ++r) {
        int tile = r * 64 + lane;
        int sl = tile / CQ, q = tile % CQ;
        float acc[VEC] = {};
#pragma unroll
        for (int k = 0; k < K; ++k) {
            float w[VEC];
            if constexpr (VEC == 4) *(float4*)w = *(const float4*)&sW[k * DC + 4 * q];
            else                    *(float2*)w = *(const float2*)&sW[k * DC + 2 * q];
            float mv = wIn[sl * KP + k];
            if constexpr (RIN) mv = fmaxf(mv, 0.f);
#pragma unroll
            for (int o = 0; o < VEC; ++o) acc[o] += mv * w[o];
        }
        int node = nodebase + sl;
        if (node < N) {
            float rr[VEC];
#pragma unroll
            for (int o = 0; o < VEC; ++o) rr[o] = fmaxf(acc[o], 0.f);
            if constexpr (VEC == 4) *(float4*)&dst[(size_t)node * DC + 4 * q] = *(float4*)rr;
            else                    *(float2*)&dst[(size_t)node * DC + 2 * q] = *(float2*)rr;
        }
    }
}

// ---- fused level body: r9 gather (byte-identical) + register-tiled GEMMs ----
template <int DIN, int DMID, int DOUT, int GSIZE, bool HAS_WA,
          int PADM, int PADA, int VEC_A, int VEC_H>
__device__ __forceinline__ void level_body(
    const float* __restrict__ hprev, float* __restrict__ hnext,
    const int* __restrict__ offsets, const int* __restrict__ csr,
    const float* __restrict__ inv_cnt,
    const float* __restrict__ Wa, const float* __restrict__ We, int N) {
    constexpr int WAVES = 8;
    constexpr int NPG = 64 / GSIZE;
    constexpr int NPB = WAVES * NPG;
    constexpr bool V2 = (DIN == 2 * GSIZE);

    __shared__ alignas(16) float sWa[HAS_WA ? DIN * DMID : 1];
    __shared__ alignas(16) float sWe[DMID * DOUT];
    __shared__ alignas(16) float sM[NPB * PADM];
    __shared__ alignas(16) float sA[HAS_WA ? NPB * PADA : 1];

    if constexpr (HAS_WA)
        for (int i = threadIdx.x; i < DIN * DMID; i += 512) sWa[i] = Wa[i];
    for (int i = threadIdx.x; i < DMID * DOUT; i += 512) sWe[i] = We[i];
    __syncthreads();

    const int lane = threadIdx.x & 63;
    const int wid  = threadIdx.x >> 6;
    const int g    = lane / GSIZE;
    const int lg   = lane & (GSIZE - 1);
    const int slot = wid * NPG + g;
    const int srcb = g * GSIZE;
    float* wM = sM + (size_t)(wid * NPG) * PADM;
    float* wA = HAS_WA ? sA + (size_t)(wid * NPG) * PADA : nullptr;
    const long stride = (long)gridDim.x * NPB;

    for (long base = (long)blockIdx.x * NPB; base < N; base += stride) {
        int node = (int)base + slot;
        if (node < N) {
            int start = offsets[node], end = offsets[node + 1];
            float m0 = 0, m1 = 0, n0 = 0, n1 = 0, p0 = 0, p1 = 0, q0 = 0, q1 = 0;
            for (int bb = start; bb < end; bb += GSIZE) {
                int cnt = min(GSIZE, end - bb);
                int sidx = (lg < cnt) ? csr[bb + lg] : 0;
                int i = 0;
                for (; i + 4 <= cnt; i += 4) {
                    int s0 = __shfl(sidx, srcb + i);
                    int s1 = __shfl(sidx, srcb + i + 1);
                    int s2 = __shfl(sidx, srcb + i + 2);
                    int s3 = __shfl(sidx, srcb + i + 3);
                    if (V2) {
                        const float2* hp = (const float2*)hprev;
                        float2 v0 = hp[(size_t)s0 * (DIN / 2) + lg];
                        float2 v1 = hp[(size_t)s1 * (DIN / 2) + lg];
                        float2 v2 = hp[(size_t)s2 * (DIN / 2) + lg];
                        float2 v3 = hp[(size_t)s3 * (DIN / 2) + lg];
                        m0 += v0.x; m1 += v0.y;
                        n0 += v1.x; n1 += v1.y;
                        p0 += v2.x; p1 += v2.y;
                        q0 += v3.x; q1 += v3.y;
                    } else if (lg < DIN) {
                        m0 += hprev[(size_t)s0 * DIN + lg];
                        n0 += hprev[(size_t)s1 * DIN + lg];
                        p0 += hprev[(size_t)s2 * DIN + lg];
                        q0 += hprev[(size_t)s3 * DIN + lg];
                    }
                }
                for (; i < cnt; ++i) {
                    int s0 = __shfl(sidx, srcb + i);
                    if (V2) {
                        const float2* hp = (const float2*)hprev;
                        float2 v0 = hp[(size_t)s0 * (DIN / 2) + lg];
                        m0 += v0.x; m1 += v0.y;
                    } else if (lg < DIN) {
                        m0 += hprev[(size_t)s0 * DIN + lg];
                    }
                }
            }
            float ic = inv_cnt[node];
            float fx = ((m0 + n0) + (p0 + q0)) * ic;
            if (V2) {
                float fy = ((m1 + n1) + (p1 + q1)) * ic;
                sM[slot * PADM + 2 * lg]     = fx;
                sM[slot * PADM + 2 * lg + 1] = fy;
            } else if (lg < DIN) {
                sM[slot * PADM + lg] = fx;
            }
        }
        const int nodebase = (int)base + wid * NPG;
        if constexpr (HAS_WA) {
            wave_mm_lds<NPG, DIN, PADM, DMID, PADA, VEC_A, false>(wM, sWa, wA, lane);
            wave_mm_gout<NPG, DMID, PADA, DOUT, VEC_H, false>(wA, sWe, hnext, nodebase, N, lane);
        } else {
            // a = relu(m) folded into the H GEMM's input read
            wave_mm_gout<NPG, DMID, PADM, DOUT, VEC_H, true>(wM, sWe, hnext, nodebase, N, lane);
        }
    }
}

// Wrappers: <DIN,DMID,DOUT,GSIZE,HAS_WA,PADM,PADA,VEC_A,VEC_H>
__global__ __launch_bounds__(512, 8) void k_lvl1(
    const float* __restrict__ hprev, float* __restrict__ hnext,
    const int* __restrict__ offsets, const int* __restrict__ csr,
    const float* __restrict__ inv_cnt, const float* __restrict__ Wa,
    const float* __restrict__ We, int N) {
    level_body<3, 32, 32, 4, true, 4, 36, 4, 4>(hprev, hnext, offsets, csr, inv_cnt, Wa, We, N);
}
__global__ __launch_bounds__(512, 8) void k_lvl2(
    const float* __restrict__ hprev, float* __restrict__ hnext,
    const int* __restrict__ offsets, const int* __restrict__ csr,
    const float* __restrict__ inv_cnt, const float* __restrict__ Wa,
    const float* __restrict__ We, int N) {
    level_body<32, 32, 64, 16, true, 34, 34, 2, 4>(hprev, hnext, offsets, csr, inv_cnt, Wa, We, N);
}
__global__ __launch_bounds__(512, 8) void k_lvl3(
    const float* __restrict__ hprev, float* __restrict__ hnext,
    const int* __restrict__ offsets, const int* __restrict__ csr,
    const float* __restrict__ inv_cnt, const float* __restrict__ Wa,
    const float* __restrict__ We, int N) {
    // PADM=PADA=64 (unpadded): slot stride 256B -> 2-way bank alias (free);
    // keeps LDS at exactly 40960B -> 4 blocks/CU as r9.
    level_body<64, 64, 64, 32, true, 64, 64, 2, 2>(hprev, hnext, offsets, csr, inv_cnt, Wa, We, N);
}
__global__ __launch_bounds__(512, 8) void k_lvl4(
    const float* __restrict__ hprev, float* __restrict__ hnext,
    const int* __restrict__ offsets, const int* __restrict__ csr,
    const float* __restrict__ inv_cnt, const float* __restrict__ Wa,
    const float* __restrict__ We, int N) {
    level_body<32, 32, 32, 16, false, 34, 34, 2, 2>(hprev, hnext, offsets, csr, inv_cnt, Wa, We, N);
}

// Dense fold: g[N x 32] = h3[N x 64] @ Wa4[64 x 32]  (no relu).
__global__ __launch_bounds__(256) void k_fold(const float* __restrict__ h3,
                                              const float* __restrict__ Wg,
                                              float* __restrict__ g, int N) {
    __shared__ float sW[64 * 32];
    __shared__ float sH[32 * 68];
    const int t = threadIdx.x;
    const int base = blockIdx.x * 32;
    for (int i = t; i < 64 * 32; i += 256) sW[i] = Wg[i];
    for (int idx = t; idx < 512; idx += 256) {
        int row = idx >> 4, q = idx & 15;
        int node = base + row;
        float4 v = (node < N) ? ((const float4*)h3)[(size_t)node * 16 + q]
                              : make_float4(0.f, 0.f, 0.f, 0.f);
        *(float4*)&sH[row * 68 + 4 * q] = v;
    }
    __syncthreads();
    const int row = t >> 3, q = t & 7;
    const int node = base + row;
    if (node < N) {
        float ax = 0.f, ay = 0.f, az = 0.f, aw = 0.f;
#pragma unroll
        for (int k = 0; k < 64; ++k) {
            float mv = sH[row * 68 + k];
            const float* w = &sW[k * 32 + 4 * q];
            ax += mv * w[0]; ay += mv * w[1]; az += mv * w[2]; aw += mv * w[3];
        }
        float4 r = make_float4(ax, ay, az, aw);
        ((float4*)g)[(size_t)node * 8 + q] = r;
    }
}

// Staged output projection.
__global__ __launch_bounds__(256, 8) void k_out(const float* __restrict__ h,
                                                const int* __restrict__ nodes,
                                                const float* __restrict__ Wout,
                                                float* __restrict__ out, int B) {
    __shared__ alignas(16) float sH[32][36];
    __shared__ float sW[32 * 40];
    __shared__ int sIdx[32];
    const int t = threadIdx.x;
    const int base = blockIdx.x * 32;
    if (t < 32) sIdx[t] = (base + t < B) ? nodes[base + t] : 0;
    for (int i = t; i < 32 * 40; i += 256) sW[i] = Wout[i];
    __syncthreads();
    {
        int g = t >> 3, lg = t & 7;
        *(float4*)&sH[g][4 * lg] = ((const float4*)h)[(size_t)sIdx[g] * 8 + lg];
    }
    __syncthreads();
#pragma unroll
    for (int j = 0; j < 5; ++j) {
        int idx = t + j * 256;
        int n = idx / 40, c = idx % 40;
        if (base + n < B) {
            float s = 0.f;
#pragma unroll
            for (int k = 0; k < 32; ++k) s += sH[n][k] * sW[k * 40 + c];
            out[(size_t)(base + n) * 40 + c] = s;
        }
    }
}

extern "C" void kernel_launch(void* const* d_in, const int* in_sizes, int n_in,
                              void* d_out, int out_size, void* d_ws, size_t ws_size,
                              hipStream_t stream) {
    const float* raw  = (const float*)d_in[0];
    const int* nodes  = (const int*)d_in[1];
    const int* esrc   = (const int*)d_in[2];
    const int* edst   = (const int*)d_in[3];
    const float* Wa1 = (const float*)d_in[4];
    const float* Wa2 = (const float*)d_in[5];
    const float* Wa3 = (const float*)d_in[6];
    const float* Wa4 = (const float*)d_in[7];
    const float* We1 = (const float*)d_in[8];
    const float* We2 = (const float*)d_in[9];
    const float* We3 = (const float*)d_in[10];
    const float* We4 = (const float*)d_in[11];
    const float* Wout = (const float*)d_in[12];
    float* out = (float*)d_out;

    int N = in_sizes[1];   // 50000
    int E = in_sizes[2];   // 850000
    int B = N;
    int nbuck = (N + (1 << BSHIFT) - 1) >> BSHIFT;

    char* p = (char*)d_ws;
    auto alloc = [&](size_t bytes) -> char* {
        char* r = p;
        p += (bytes + 255) & ~(size_t)255;
        return r;
    };
    int*   deg     = (int*)alloc((size_t)N * 4);
    int*   offsets = (int*)alloc((size_t)(N + 1) * 4);
    float* inv_cnt = (float*)alloc((size_t)N * 4);
    int NB = (N + 1023) / 1024;
    int*   bsums   = (int*)alloc((size_t)NB * 4);
    int*   bcur    = (int*)alloc((size_t)MAXBUCK * 4);
    int*   csr     = (int*)alloc((size_t)E * 4);
    float* bufA    = (float*)alloc((size_t)N * 64 * 4);
    float* bufB    = (float*)alloc((size_t)N * 64 * 4);
    float* bufC    = (float*)alloc((size_t)N * 32 * 4);
    (void)ws_size; (void)n_in; (void)out_size;

    int2* staging = (int2*)bufA;   // dead before k_lvl1 writes h1

    hipMemsetAsync(deg, 0, (size_t)N * 4, stream);
    int eb256 = (E + 255) / 256;
    int eb512 = (E + 511) / 512;
    k_count<<<eb256, 256, 0, stream>>>(edst, deg, E);
    k_blocksum<<<NB, 256, 0, stream>>>(deg, bsums, N);
    k_scantop<<<1, 256, 0, stream>>>(bsums, NB);
    k_scanfinal<<<NB, 256, 0, stream>>>(deg, bsums, offsets, inv_cnt, N, E);
    k_binit<<<(nbuck + 255) / 256, 256, 0, stream>>>(offsets, bcur, nbuck, N);
    k_bucket<<<eb512, 512, 0, stream>>>(esrc, edst, bcur, staging, nbuck, E);
    k_place<<<nbuck, 512, 0, stream>>>(staging, offsets, csr, N, E);

    auto blocksFor = [](int n, int npb) {
        int b = (n + npb - 1) / npb;
        return b < 2048 ? b : 2048;
    };

    float* h1 = bufA;  // [N x 32]
    float* h2 = bufB;  // [N x 64]
    float* h3 = bufA;  // [N x 64]
    float* g_ = bufC;  // [N x 32]
    float* h4 = bufB;  // [N x 32]

    k_lvl1<<<blocksFor(N, 128), 512, 0, stream>>>(raw, h1, offsets, csr, inv_cnt, Wa1, We1, N);
    k_lvl2<<<blocksFor(N, 32), 512, 0, stream>>>(h1, h2, offsets, csr, inv_cnt, Wa2, We2, N);
    k_lvl3<<<blocksFor(N, 16), 512, 0, stream>>>(h2, h3, offsets, csr, inv_cnt, Wa3, We3, N);
    k_fold<<<(N + 31) / 32, 256, 0, stream>>>(h3, Wa4, g_, N);
    k_lvl4<<<blocksFor(N, 32), 512, 0, stream>>>(g_, h4, offsets, csr, inv_cnt, nullptr, We4, N);

    k_out<<<(B + 31) / 32, 256, 0, stream>>>(h4, nodes, Wout, out, B);
}

// Round 11
// 245.788 us; speedup vs baseline: 2.5312x; 2.5312x over previous
//
#include <hip/hip_runtime.h>

// GraphSAGE forward — round 11: r9 champion, byte-identical level-kernel
// gather/store/GEMM code, with the algebraic fold extended to L2 and L3:
//   g1 = h1@Wa2 (dense) -> lvl2 runs HAS_WA=false (the lvl4-proven config)
//   g2 = h2@Wa3 (dense) -> lvl3 runs HAS_WA=false
//   g3 = h3@Wa4 (dense) -> lvl4 (as r9)
//
// Hard-won invariants:
//  - Gather reads ONE full contiguous row per vmem instruction, indices
//    shfl-broadcast (r3/r4: FETCH 199-636MB when violated).
//  - Gather stays fused with level GEMM at moderate occupancy (r7 split
//    doubled HBM traffic; r10's lighter GEMM+new writer exploded traffic).
//  - NEVER replace the store path: r10's register-tiled writer produced
//    618MB of writes for 12.5MB of data. The r2/r9 scalar H-phase writer
//    and relu-copy A-phase (lvl4 config) are the only proven-safe bodies.
//  - Scattered 4B writes cost a 64B line each -> bucketed CSR build (r9).
//  - mean_agg(h)@W == mean_agg(h@W), fp32-validated r5-r9 (absmax 3e-5).

#define BSHIFT 9
#define MAXBUCK 256

__global__ __launch_bounds__(256) void k_count(const int* __restrict__ edst,
                                               int* __restrict__ deg, int E) {
    int t = blockIdx.x * blockDim.x + threadIdx.x;
    if (t < E) atomicAdd(&deg[edst[t]], 1);
}

__global__ __launch_bounds__(256) void k_blocksum(const int* __restrict__ deg,
                                                  int* __restrict__ bsums, int N) {
    __shared__ int s[256];
    int t = threadIdx.x;
    int base = blockIdx.x * 1024 + t * 4;
    int v = 0;
#pragma unroll
    for (int j = 0; j < 4; j++) { int idx = base + j; if (idx < N) v += deg[idx]; }
    s[t] = v; __syncthreads();
    for (int o = 128; o > 0; o >>= 1) { if (t < o) s[t] += s[t + o]; __syncthreads(); }
    if (t == 0) bsums[blockIdx.x] = s[0];
}

__global__ __launch_bounds__(256) void k_scantop(int* __restrict__ bsums, int NB) {
    __shared__ int s[256];
    int t = threadIdx.x;
    int v = (t < NB) ? bsums[t] : 0;
    s[t] = v; __syncthreads();
    for (int o = 1; o < 256; o <<= 1) {
        int x = (t >= o) ? s[t - o] : 0;
        __syncthreads();
        s[t] += x;
        __syncthreads();
    }
    if (t < NB) bsums[t] = s[t] - v;
}

__global__ __launch_bounds__(256) void k_scanfinal(const int* __restrict__ deg,
                                                   const int* __restrict__ bsums,
                                                   int* __restrict__ offsets,
                                                   float* __restrict__ inv_cnt,
                                                   int N, int E) {
    __shared__ int s[256];
    int t = threadIdx.x, b = blockIdx.x;
    int base = b * 1024 + t * 4;
    int d[4]; int lsum = 0;
#pragma unroll
    for (int j = 0; j < 4; j++) { int idx = base + j; d[j] = (idx < N) ? deg[idx] : 0; lsum += d[j]; }
    s[t] = lsum; __syncthreads();
    for (int o = 1; o < 256; o <<= 1) {
        int x = (t >= o) ? s[t - o] : 0;
        __syncthreads();
        s[t] += x;
        __syncthreads();
    }
    int p = bsums[b] + s[t] - lsum;
#pragma unroll
    for (int j = 0; j < 4; j++) {
        int idx = base + j;
        if (idx < N) {
            offsets[idx] = p;
            inv_cnt[idx] = 1.0f / (float)(d[j] > 0 ? d[j] : 1);
            p += d[j];
        }
    }
    if (b == 0 && t == 0) offsets[N] = E;
}

__global__ __launch_bounds__(256) void k_binit(const int* __restrict__ offsets,
                                               int* __restrict__ bcur, int nbuck, int N) {
    int b = blockIdx.x * blockDim.x + threadIdx.x;
    if (b < nbuck) {
        int node = b << BSHIFT;
        bcur[b] = offsets[node < N ? node : N];
    }
}

__global__ __launch_bounds__(512) void k_bucket(const int* __restrict__ esrc,
                                                const int* __restrict__ edst,
                                                int* __restrict__ bcur,
                                                int2* __restrict__ staging,
                                                int nbuck, int E) {
    __shared__ int hist[MAXBUCK];
    __shared__ int bbase[MAXBUCK];
    const int t = threadIdx.x;
    const int e = blockIdx.x * 512 + t;
    int src = 0, dst = 0, b = 0;
    if (e < E) { src = esrc[e]; dst = edst[e]; b = dst >> BSHIFT; }
    for (int i = t; i < nbuck; i += 512) hist[i] = 0;
    __syncthreads();
    int rank = 0;
    if (e < E) rank = atomicAdd(&hist[b], 1);
    __syncthreads();
    for (int i = t; i < nbuck; i += 512)
        bbase[i] = hist[i] ? atomicAdd(&bcur[i], hist[i]) : 0;
    __syncthreads();
    if (e < E) staging[bbase[b] + rank] = make_int2(src, dst);
}

__global__ __launch_bounds__(512) void k_place(const int2* __restrict__ staging,
                                               const int* __restrict__ offsets,
                                               int* __restrict__ csr, int N, int E) {
    __shared__ int cur[1 << BSHIFT];
    const int t = threadIdx.x;
    const int nbase = blockIdx.x << BSHIFT;
    const int nend = min(nbase + (1 << BSHIFT), N);
    for (int i = t; i < nend - nbase; i += 512) cur[i] = offsets[nbase + i];
    __syncthreads();
    const int estart = offsets[nbase], eend = offsets[nend];
    for (int e = estart + t; e < eend; e += 512) {
        int2 pr = staging[e];
        int pos = atomicAdd(&cur[pr.y - nbase], 1);
        csr[pos] = pr.x;
    }
}

// ---- r2/r9 proven fused level body (byte-identical; wave-private slots) ----
template <int DIN, int DMID, int DOUT, int GSIZE, bool HAS_WA>
__device__ __forceinline__ void level_body(
    const float* __restrict__ hprev, float* __restrict__ hnext,
    const int* __restrict__ offsets, const int* __restrict__ csr,
    const float* __restrict__ inv_cnt,
    const float* __restrict__ Wa, const float* __restrict__ We, int N) {
    constexpr int WAVES = 8;
    constexpr int NPG = 64 / GSIZE;   // nodes per wave
    constexpr int NPB = WAVES * NPG;  // nodes per block
    constexpr bool V2 = (DIN == 2 * GSIZE);

    __shared__ float sWa[HAS_WA ? DIN * DMID : 1];
    __shared__ float sWe[DMID * DOUT];
    __shared__ float sM[NPB * DIN];   // wave-private slots
    __shared__ float sA[NPB * DMID];  // wave-private slots

    if constexpr (HAS_WA)
        for (int i = threadIdx.x; i < DIN * DMID; i += 512) sWa[i] = Wa[i];
    for (int i = threadIdx.x; i < DMID * DOUT; i += 512) sWe[i] = We[i];
    __syncthreads();

    const int lane = threadIdx.x & 63;
    const int wid  = threadIdx.x >> 6;
    const int g    = lane / GSIZE;
    const int lg   = lane & (GSIZE - 1);
    const int slot = wid * NPG + g;
    const int srcb = g * GSIZE;
    const long stride = (long)gridDim.x * NPB;

    for (long base = (long)blockIdx.x * NPB; base < N; base += stride) {
        int node = (int)base + slot;
        if (node < N) {
            int start = offsets[node], end = offsets[node + 1];
            float m0 = 0, m1 = 0, n0 = 0, n1 = 0, p0 = 0, p1 = 0, q0 = 0, q1 = 0;
            for (int bb = start; bb < end; bb += GSIZE) {
                int cnt = min(GSIZE, end - bb);
                int sidx = (lg < cnt) ? csr[bb + lg] : 0;
                int i = 0;
                for (; i + 4 <= cnt; i += 4) {
                    int s0 = __shfl(sidx, srcb + i);
                    int s1 = __shfl(sidx, srcb + i + 1);
                    int s2 = __shfl(sidx, srcb + i + 2);
                    int s3 = __shfl(sidx, srcb + i + 3);
                    if (V2) {
                        const float2* hp = (const float2*)hprev;
                        float2 v0 = hp[(size_t)s0 * (DIN / 2) + lg];
                        float2 v1 = hp[(size_t)s1 * (DIN / 2) + lg];
                        float2 v2 = hp[(size_t)s2 * (DIN / 2) + lg];
                        float2 v3 = hp[(size_t)s3 * (DIN / 2) + lg];
                        m0 += v0.x; m1 += v0.y;
                        n0 += v1.x; n1 += v1.y;
                        p0 += v2.x; p1 += v2.y;
                        q0 += v3.x; q1 += v3.y;
                    } else if (lg < DIN) {
                        m0 += hprev[(size_t)s0 * DIN + lg];
                        n0 += hprev[(size_t)s1 * DIN + lg];
                        p0 += hprev[(size_t)s2 * DIN + lg];
                        q0 += hprev[(size_t)s3 * DIN + lg];
                    }
                }
                for (; i < cnt; ++i) {
                    int s0 = __shfl(sidx, srcb + i);
                    if (V2) {
                        const float2* hp = (const float2*)hprev;
                        float2 v0 = hp[(size_t)s0 * (DIN / 2) + lg];
                        m0 += v0.x; m1 += v0.y;
                    } else if (lg < DIN) {
                        m0 += hprev[(size_t)s0 * DIN + lg];
                    }
                }
            }
            float ic = inv_cnt[node];
            float fx = ((m0 + n0) + (p0 + q0)) * ic;
            if (V2) {
                float fy = ((m1 + n1) + (p1 + q1)) * ic;
                sM[slot * DIN + 2 * lg]     = fx;
                sM[slot * DIN + 2 * lg + 1] = fy;
            } else if (lg < DIN) {
                sM[slot * DIN + lg] = fx;
            }
        }
        // a = relu(m @ Wa)  (or a = relu(m) when Wa is folded upstream)
        constexpr int AO = NPG * DMID;
#pragma unroll
        for (int r = 0; r < AO / 64; ++r) {
            int oi = r * 64 + lane;
            int sl = wid * NPG + oi / DMID;
            int col = oi & (DMID - 1);
            if ((int)base + sl < N) {
                if constexpr (HAS_WA) {
                    float v = 0.f;
#pragma unroll
                    for (int k = 0; k < DIN; ++k) v += sM[sl * DIN + k] * sWa[k * DMID + col];
                    sA[sl * DMID + col] = fmaxf(v, 0.f);
                } else {
                    sA[sl * DMID + col] = fmaxf(sM[sl * DIN + col], 0.f);
                }
            }
        }
        // h = relu(a @ We)
        constexpr int HO = NPG * DOUT;
#pragma unroll
        for (int r = 0; r < HO / 64; ++r) {
            int oi = r * 64 + lane;
            int sl = wid * NPG + oi / DOUT;
            int col = oi & (DOUT - 1);
            int nd = (int)base + sl;
            if (nd < N) {
                float v = 0.f;
#pragma unroll
                for (int k = 0; k < DMID; ++k) v += sA[sl * DMID + k] * sWe[k * DOUT + col];
                hnext[(size_t)nd * DOUT + col] = fmaxf(v, 0.f);
            }
        }
    }
}

// Wrappers. lvl2/lvl3 now run the lvl4-proven HAS_WA=false config.
__global__ __launch_bounds__(512, 8) void k_lvl1(
    const float* __restrict__ hprev, float* __restrict__ hnext,
    const int* __restrict__ offsets, const int* __restrict__ csr,
    const float* __restrict__ inv_cnt, const float* __restrict__ Wa,
    const float* __restrict__ We, int N) {
    level_body<3, 32, 32, 4, true>(hprev, hnext, offsets, csr, inv_cnt, Wa, We, N);
}
__global__ __launch_bounds__(512, 8) void k_lvl2(
    const float* __restrict__ hprev, float* __restrict__ hnext,
    const int* __restrict__ offsets, const int* __restrict__ csr,
    const float* __restrict__ inv_cnt, const float* __restrict__ Wa,
    const float* __restrict__ We, int N) {
    level_body<32, 32, 64, 16, false>(hprev, hnext, offsets, csr, inv_cnt, Wa, We, N);
}
__global__ __launch_bounds__(512, 8) void k_lvl3(
    const float* __restrict__ hprev, float* __restrict__ hnext,
    const int* __restrict__ offsets, const int* __restrict__ csr,
    const float* __restrict__ inv_cnt, const float* __restrict__ Wa,
    const float* __restrict__ We, int N) {
    level_body<64, 64, 64, 32, false>(hprev, hnext, offsets, csr, inv_cnt, Wa, We, N);
}
__global__ __launch_bounds__(512, 8) void k_lvl4(
    const float* __restrict__ hprev, float* __restrict__ hnext,
    const int* __restrict__ offsets, const int* __restrict__ csr,
    const float* __restrict__ inv_cnt, const float* __restrict__ Wa,
    const float* __restrict__ We, int N) {
    level_body<32, 32, 32, 16, false>(hprev, hnext, offsets, csr, inv_cnt, Wa, We, N);
}

// Dense fold (pattern-cloned from r9's proven k_fold): g = h @ W, no relu.
// 32 nodes/block; thread computes float4 of output cols.
template <int KIN, int DCO>
__global__ __launch_bounds__(256) void k_foldT(const float* __restrict__ hin,
                                               const float* __restrict__ W,
                                               float* __restrict__ gout, int N) {
    constexpr int PAD = KIN + 4;
    __shared__ float sW[KIN * DCO];
    __shared__ alignas(16) float sH[32 * PAD];
    const int t = threadIdx.x;
    const int base = blockIdx.x * 32;
    for (int i = t; i < KIN * DCO; i += 256) sW[i] = W[i];
    constexpr int RQ = KIN / 4;
    for (int idx = t; idx < 32 * RQ; idx += 256) {
        int row = idx / RQ, q = idx % RQ;
        int node = base + row;
        float4 v = (node < N) ? ((const float4*)hin)[(size_t)node * RQ + q]
                              : make_float4(0.f, 0.f, 0.f, 0.f);
        *(float4*)&sH[row * PAD + 4 * q] = v;
    }
    __syncthreads();
    constexpr int CQ = DCO / 4;
    constexpr int TILES = 32 * CQ;
#pragma unroll
    for (int j = 0; j < (TILES + 255) / 256; ++j) {
        int idx = t + j * 256;
        if (TILES % 256 == 0 || idx < TILES) {
            int row = idx / CQ, q = idx % CQ;
            int node = base + row;
            if (node < N) {
                float a0 = 0.f, a1 = 0.f, a2 = 0.f, a3 = 0.f;
#pragma unroll
                for (int k = 0; k < KIN; ++k) {
                    float mv = sH[row * PAD + k];
                    const float* w = &sW[k * DCO + 4 * q];
                    a0 += mv * w[0]; a1 += mv * w[1];
                    a2 += mv * w[2]; a3 += mv * w[3];
                }
                float4 r = make_float4(a0, a1, a2, a3);
                *(float4*)&gout[(size_t)node * DCO + 4 * q] = r;
            }
        }
    }
}

// Staged output projection (unchanged).
__global__ __launch_bounds__(256, 8) void k_out(const float* __restrict__ h,
                                                const int* __restrict__ nodes,
                                                const float* __restrict__ Wout,
                                                float* __restrict__ out, int B) {
    __shared__ alignas(16) float sH[32][36];
    __shared__ float sW[32 * 40];
    __shared__ int sIdx[32];
    const int t = threadIdx.x;
    const int base = blockIdx.x * 32;
    if (t < 32) sIdx[t] = (base + t < B) ? nodes[base + t] : 0;
    for (int i = t; i < 32 * 40; i += 256) sW[i] = Wout[i];
    __syncthreads();
    {
        int g = t >> 3, lg = t & 7;
        *(float4*)&sH[g][4 * lg] = ((const float4*)h)[(size_t)sIdx[g] * 8 + lg];
    }
    __syncthreads();
#pragma unroll
    for (int j = 0; j < 5; ++j) {
        int idx = t + j * 256;
        int n = idx / 40, c = idx % 40;
        if (base + n < B) {
            float s = 0.f;
#pragma unroll
            for (int k = 0; k < 32; ++k) s += sH[n][k] * sW[k * 40 + c];
            out[(size_t)(base + n) * 40 + c] = s;
        }
    }
}

extern "C" void kernel_launch(void* const* d_in, const int* in_sizes, int n_in,
                              void* d_out, int out_size, void* d_ws, size_t ws_size,
                              hipStream_t stream) {
    const float* raw  = (const float*)d_in[0];
    const int* nodes  = (const int*)d_in[1];
    const int* esrc   = (const int*)d_in[2];
    const int* edst   = (const int*)d_in[3];
    const float* Wa1 = (const float*)d_in[4];
    const float* Wa2 = (const float*)d_in[5];
    const float* Wa3 = (const float*)d_in[6];
    const float* Wa4 = (const float*)d_in[7];
    const float* We1 = (const float*)d_in[8];
    const float* We2 = (const float*)d_in[9];
    const float* We3 = (const float*)d_in[10];
    const float* We4 = (const float*)d_in[11];
    const float* Wout = (const float*)d_in[12];
    float* out = (float*)d_out;

    int N = in_sizes[1];   // 50000
    int E = in_sizes[2];   // 850000
    int B = N;
    int nbuck = (N + (1 << BSHIFT) - 1) >> BSHIFT;

    char* p = (char*)d_ws;
    auto alloc = [&](size_t bytes) -> char* {
        char* r = p;
        p += (bytes + 255) & ~(size_t)255;
        return r;
    };
    int*   deg     = (int*)alloc((size_t)N * 4);
    int*   offsets = (int*)alloc((size_t)(N + 1) * 4);
    float* inv_cnt = (float*)alloc((size_t)N * 4);
    int NB = (N + 1023) / 1024;
    int*   bsums   = (int*)alloc((size_t)NB * 4);
    int*   bcur    = (int*)alloc((size_t)MAXBUCK * 4);
    int*   csr     = (int*)alloc((size_t)E * 4);
    float* bufA    = (float*)alloc((size_t)N * 64 * 4);  // 12.8MB
    float* bufB    = (float*)alloc((size_t)N * 64 * 4);  // 12.8MB
    float* bufC    = (float*)alloc((size_t)N * 32 * 4);  // 6.4MB
    (void)ws_size; (void)n_in; (void)out_size;

    int2* staging = (int2*)bufA;   // 6.8MB overlay; dead before lvl2 writes bufA

    hipMemsetAsync(deg, 0, (size_t)N * 4, stream);
    int eb256 = (E + 255) / 256;
    int eb512 = (E + 511) / 512;
    k_count<<<eb256, 256, 0, stream>>>(edst, deg, E);
    k_blocksum<<<NB, 256, 0, stream>>>(deg, bsums, N);
    k_scantop<<<1, 256, 0, stream>>>(bsums, NB);
    k_scanfinal<<<NB, 256, 0, stream>>>(deg, bsums, offsets, inv_cnt, N, E);
    k_binit<<<(nbuck + 255) / 256, 256, 0, stream>>>(offsets, bcur, nbuck, N);
    k_bucket<<<eb512, 512, 0, stream>>>(esrc, edst, bcur, staging, nbuck, E);
    k_place<<<nbuck, 512, 0, stream>>>(staging, offsets, csr, N, E);

    auto blocksFor = [](int n, int npb) {
        int b = (n + npb - 1) / npb;
        return b < 2048 ? b : 2048;
    };
    int fb = (N + 31) / 32;

    // Buffer timeline (no aliasing hazards):
    //   h1 = bufB[0:N*32]   (lvl1 out; staging in bufA still live until k_place done)
    //   g1 = bufC           (fold2: h1@Wa2)
    //   h2 = bufA           (lvl2 out; staging dead)
    //   g2 = bufB           (fold3: h2@Wa3; overwrites h1, dead)
    //   h3 = bufA           (lvl3 out; overwrites h2, dead after fold3)
    //   g3 = bufC           (fold4: h3@Wa4; overwrites g1, dead)
    //   h4 = bufB[0:N*32]   (lvl4 out; overwrites g2, dead)
    float* h1 = bufB;
    float* g1 = bufC;
    float* h2 = bufA;
    float* g2 = bufB;
    float* h3 = bufA;
    float* g3 = bufC;
    float* h4 = bufB;

    // L1: raw(3) -> h1(32)  (keeps Wa1: raw rows are 12B, L2-resident)
    k_lvl1<<<blocksFor(N, 128), 512, 0, stream>>>(raw, h1, offsets, csr, inv_cnt, Wa1, We1, N);
    // fold2: g1 = h1 @ Wa2
    k_foldT<32, 32><<<fb, 256, 0, stream>>>(h1, Wa2, g1, N);
    // L2: gather g1(32) -> h2(64), Wa absorbed
    k_lvl2<<<blocksFor(N, 32), 512, 0, stream>>>(g1, h2, offsets, csr, inv_cnt, nullptr, We2, N);
    // fold3: g2 = h2 @ Wa3
    k_foldT<64, 64><<<fb, 256, 0, stream>>>(h2, Wa3, g2, N);
    // L3: gather g2(64) -> h3(64), Wa absorbed
    k_lvl3<<<blocksFor(N, 16), 512, 0, stream>>>(g2, h3, offsets, csr, inv_cnt, nullptr, We3, N);
    // fold4: g3 = h3 @ Wa4
    k_foldT<64, 32><<<fb, 256, 0, stream>>>(h3, Wa4, g3, N);
    // L4: gather g3(32) -> h4(32), Wa absorbed
    k_lvl4<<<blocksFor(N, 32), 512, 0, stream>>>(g3, h4, offsets, csr, inv_cnt, nullptr, We4, N);

    k_out<<<(B + 31) / 32, 256, 0, stream>>>(h4, nodes, Wout, out, B);
}

// Round 12
// 244.322 us; speedup vs baseline: 2.5464x; 1.0060x over previous
//
#include <hip/hip_runtime.h>

// GraphSAGE forward — round 12: r11 (= r9 champion + Wa-folds), with the
// 44µs rocclr fillBuffer (hipMemsetAsync of deg, 195KB!) replaced by a
// custom vectorized zero kernel. Everything else byte-identical to r11.
//
// Hard-won invariants:
//  - Gather reads ONE full contiguous row per vmem instruction, indices
//    shfl-broadcast (r3/r4: FETCH 199-636MB when violated).
//  - Gather stays fused with level GEMM at moderate occupancy (r7 split
//    doubled HBM traffic; r10's new writer exploded write traffic 50x).
//  - NEVER replace the proven store path / level-kernel body (r10: 618MB
//    writes). r2/r9 scalar H-phase + relu-copy A-phase only.
//  - Scattered 4B writes cost a 64B line each -> bucketed CSR build (r9).
//  - mean_agg(h)@W == mean_agg(h@W): all four Wa folded (r11, absmax 3e-5).
//  - hipMemsetAsync as first graph node cost 44µs for 200KB (r11 profile);
//    custom k_zero instead.

#define BSHIFT 9
#define MAXBUCK 256

__global__ __launch_bounds__(256) void k_zero(int4* __restrict__ p, int n4) {
    int i = blockIdx.x * 256 + threadIdx.x;
    if (i < n4) p[i] = make_int4(0, 0, 0, 0);
}

__global__ __launch_bounds__(256) void k_count(const int* __restrict__ edst,
                                               int* __restrict__ deg, int E) {
    int t = blockIdx.x * blockDim.x + threadIdx.x;
    if (t < E) atomicAdd(&deg[edst[t]], 1);
}

__global__ __launch_bounds__(256) void k_blocksum(const int* __restrict__ deg,
                                                  int* __restrict__ bsums, int N) {
    __shared__ int s[256];
    int t = threadIdx.x;
    int base = blockIdx.x * 1024 + t * 4;
    int v = 0;
#pragma unroll
    for (int j = 0; j < 4; j++) { int idx = base + j; if (idx < N) v += deg[idx]; }
    s[t] = v; __syncthreads();
    for (int o = 128; o > 0; o >>= 1) { if (t < o) s[t] += s[t + o]; __syncthreads(); }
    if (t == 0) bsums[blockIdx.x] = s[0];
}

__global__ __launch_bounds__(256) void k_scantop(int* __restrict__ bsums, int NB) {
    __shared__ int s[256];
    int t = threadIdx.x;
    int v = (t < NB) ? bsums[t] : 0;
    s[t] = v; __syncthreads();
    for (int o = 1; o < 256; o <<= 1) {
        int x = (t >= o) ? s[t - o] : 0;
        __syncthreads();
        s[t] += x;
        __syncthreads();
    }
    if (t < NB) bsums[t] = s[t] - v;
}

__global__ __launch_bounds__(256) void k_scanfinal(const int* __restrict__ deg,
                                                   const int* __restrict__ bsums,
                                                   int* __restrict__ offsets,
                                                   float* __restrict__ inv_cnt,
                                                   int N, int E) {
    __shared__ int s[256];
    int t = threadIdx.x, b = blockIdx.x;
    int base = b * 1024 + t * 4;
    int d[4]; int lsum = 0;
#pragma unroll
    for (int j = 0; j < 4; j++) { int idx = base + j; d[j] = (idx < N) ? deg[idx] : 0; lsum += d[j]; }
    s[t] = lsum; __syncthreads();
    for (int o = 1; o < 256; o <<= 1) {
        int x = (t >= o) ? s[t - o] : 0;
        __syncthreads();
        s[t] += x;
        __syncthreads();
    }
    int p = bsums[b] + s[t] - lsum;
#pragma unroll
    for (int j = 0; j < 4; j++) {
        int idx = base + j;
        if (idx < N) {
            offsets[idx] = p;
            inv_cnt[idx] = 1.0f / (float)(d[j] > 0 ? d[j] : 1);
            p += d[j];
        }
    }
    if (b == 0 && t == 0) offsets[N] = E;
}

__global__ __launch_bounds__(256) void k_binit(const int* __restrict__ offsets,
                                               int* __restrict__ bcur, int nbuck, int N) {
    int b = blockIdx.x * blockDim.x + threadIdx.x;
    if (b < nbuck) {
        int node = b << BSHIFT;
        bcur[b] = offsets[node < N ? node : N];
    }
}

__global__ __launch_bounds__(512) void k_bucket(const int* __restrict__ esrc,
                                                const int* __restrict__ edst,
                                                int* __restrict__ bcur,
                                                int2* __restrict__ staging,
                                                int nbuck, int E) {
    __shared__ int hist[MAXBUCK];
    __shared__ int bbase[MAXBUCK];
    const int t = threadIdx.x;
    const int e = blockIdx.x * 512 + t;
    int src = 0, dst = 0, b = 0;
    if (e < E) { src = esrc[e]; dst = edst[e]; b = dst >> BSHIFT; }
    for (int i = t; i < nbuck; i += 512) hist[i] = 0;
    __syncthreads();
    int rank = 0;
    if (e < E) rank = atomicAdd(&hist[b], 1);
    __syncthreads();
    for (int i = t; i < nbuck; i += 512)
        bbase[i] = hist[i] ? atomicAdd(&bcur[i], hist[i]) : 0;
    __syncthreads();
    if (e < E) staging[bbase[b] + rank] = make_int2(src, dst);
}

__global__ __launch_bounds__(512) void k_place(const int2* __restrict__ staging,
                                               const int* __restrict__ offsets,
                                               int* __restrict__ csr, int N, int E) {
    __shared__ int cur[1 << BSHIFT];
    const int t = threadIdx.x;
    const int nbase = blockIdx.x << BSHIFT;
    const int nend = min(nbase + (1 << BSHIFT), N);
    for (int i = t; i < nend - nbase; i += 512) cur[i] = offsets[nbase + i];
    __syncthreads();
    const int estart = offsets[nbase], eend = offsets[nend];
    for (int e = estart + t; e < eend; e += 512) {
        int2 pr = staging[e];
        int pos = atomicAdd(&cur[pr.y - nbase], 1);
        csr[pos] = pr.x;
    }
}

// ---- r2/r9 proven fused level body (byte-identical; wave-private slots) ----
template <int DIN, int DMID, int DOUT, int GSIZE, bool HAS_WA>
__device__ __forceinline__ void level_body(
    const float* __restrict__ hprev, float* __restrict__ hnext,
    const int* __restrict__ offsets, const int* __restrict__ csr,
    const float* __restrict__ inv_cnt,
    const float* __restrict__ Wa, const float* __restrict__ We, int N) {
    constexpr int WAVES = 8;
    constexpr int NPG = 64 / GSIZE;   // nodes per wave
    constexpr int NPB = WAVES * NPG;  // nodes per block
    constexpr bool V2 = (DIN == 2 * GSIZE);

    __shared__ float sWa[HAS_WA ? DIN * DMID : 1];
    __shared__ float sWe[DMID * DOUT];
    __shared__ float sM[NPB * DIN];   // wave-private slots
    __shared__ float sA[NPB * DMID];  // wave-private slots

    if constexpr (HAS_WA)
        for (int i = threadIdx.x; i < DIN * DMID; i += 512) sWa[i] = Wa[i];
    for (int i = threadIdx.x; i < DMID * DOUT; i += 512) sWe[i] = We[i];
    __syncthreads();

    const int lane = threadIdx.x & 63;
    const int wid  = threadIdx.x >> 6;
    const int g    = lane / GSIZE;
    const int lg   = lane & (GSIZE - 1);
    const int slot = wid * NPG + g;
    const int srcb = g * GSIZE;
    const long stride = (long)gridDim.x * NPB;

    for (long base = (long)blockIdx.x * NPB; base < N; base += stride) {
        int node = (int)base + slot;
        if (node < N) {
            int start = offsets[node], end = offsets[node + 1];
            float m0 = 0, m1 = 0, n0 = 0, n1 = 0, p0 = 0, p1 = 0, q0 = 0, q1 = 0;
            for (int bb = start; bb < end; bb += GSIZE) {
                int cnt = min(GSIZE, end - bb);
                int sidx = (lg < cnt) ? csr[bb + lg] : 0;
                int i = 0;
                for (; i + 4 <= cnt; i += 4) {
                    int s0 = __shfl(sidx, srcb + i);
                    int s1 = __shfl(sidx, srcb + i + 1);
                    int s2 = __shfl(sidx, srcb + i + 2);
                    int s3 = __shfl(sidx, srcb + i + 3);
                    if (V2) {
                        const float2* hp = (const float2*)hprev;
                        float2 v0 = hp[(size_t)s0 * (DIN / 2) + lg];
                        float2 v1 = hp[(size_t)s1 * (DIN / 2) + lg];
                        float2 v2 = hp[(size_t)s2 * (DIN / 2) + lg];
                        float2 v3 = hp[(size_t)s3 * (DIN / 2) + lg];
                        m0 += v0.x; m1 += v0.y;
                        n0 += v1.x; n1 += v1.y;
                        p0 += v2.x; p1 += v2.y;
                        q0 += v3.x; q1 += v3.y;
                    } else if (lg < DIN) {
                        m0 += hprev[(size_t)s0 * DIN + lg];
                        n0 += hprev[(size_t)s1 * DIN + lg];
                        p0 += hprev[(size_t)s2 * DIN + lg];
                        q0 += hprev[(size_t)s3 * DIN + lg];
                    }
                }
                for (; i < cnt; ++i) {
                    int s0 = __shfl(sidx, srcb + i);
                    if (V2) {
                        const float2* hp = (const float2*)hprev;
                        float2 v0 = hp[(size_t)s0 * (DIN / 2) + lg];
                        m0 += v0.x; m1 += v0.y;
                    } else if (lg < DIN) {
                        m0 += hprev[(size_t)s0 * DIN + lg];
                    }
                }
            }
            float ic = inv_cnt[node];
            float fx = ((m0 + n0) + (p0 + q0)) * ic;
            if (V2) {
                float fy = ((m1 + n1) + (p1 + q1)) * ic;
                sM[slot * DIN + 2 * lg]     = fx;
                sM[slot * DIN + 2 * lg + 1] = fy;
            } else if (lg < DIN) {
                sM[slot * DIN + lg] = fx;
            }
        }
        // a = relu(m @ Wa)  (or a = relu(m) when Wa is folded upstream)
        constexpr int AO = NPG * DMID;
#pragma unroll
        for (int r = 0; r < AO / 64; ++r) {
            int oi = r * 64 + lane;
            int sl = wid * NPG + oi / DMID;
            int col = oi & (DMID - 1);
            if ((int)base + sl < N) {
                if constexpr (HAS_WA) {
                    float v = 0.f;
#pragma unroll
                    for (int k = 0; k < DIN; ++k) v += sM[sl * DIN + k] * sWa[k * DMID + col];
                    sA[sl * DMID + col] = fmaxf(v, 0.f);
                } else {
                    sA[sl * DMID + col] = fmaxf(sM[sl * DIN + col], 0.f);
                }
            }
        }
        // h = relu(a @ We)
        constexpr int HO = NPG * DOUT;
#pragma unroll
        for (int r = 0; r < HO / 64; ++r) {
            int oi = r * 64 + lane;
            int sl = wid * NPG + oi / DOUT;
            int col = oi & (DOUT - 1);
            int nd = (int)base + sl;
            if (nd < N) {
                float v = 0.f;
#pragma unroll
                for (int k = 0; k < DMID; ++k) v += sA[sl * DMID + k] * sWe[k * DOUT + col];
                hnext[(size_t)nd * DOUT + col] = fmaxf(v, 0.f);
            }
        }
    }
}

// Wrappers. lvl2/lvl3/lvl4 run the proven HAS_WA=false config (Wa folded).
__global__ __launch_bounds__(512, 8) void k_lvl1(
    const float* __restrict__ hprev, float* __restrict__ hnext,
    const int* __restrict__ offsets, const int* __restrict__ csr,
    const float* __restrict__ inv_cnt, const float* __restrict__ Wa,
    const float* __restrict__ We, int N) {
    level_body<3, 32, 32, 4, true>(hprev, hnext, offsets, csr, inv_cnt, Wa, We, N);
}
__global__ __launch_bounds__(512, 8) void k_lvl2(
    const float* __restrict__ hprev, float* __restrict__ hnext,
    const int* __restrict__ offsets, const int* __restrict__ csr,
    const float* __restrict__ inv_cnt, const float* __restrict__ Wa,
    const float* __restrict__ We, int N) {
    level_body<32, 32, 64, 16, false>(hprev, hnext, offsets, csr, inv_cnt, Wa, We, N);
}
__global__ __launch_bounds__(512, 8) void k_lvl3(
    const float* __restrict__ hprev, float* __restrict__ hnext,
    const int* __restrict__ offsets, const int* __restrict__ csr,
    const float* __restrict__ inv_cnt, const float* __restrict__ Wa,
    const float* __restrict__ We, int N) {
    level_body<64, 64, 64, 32, false>(hprev, hnext, offsets, csr, inv_cnt, Wa, We, N);
}
__global__ __launch_bounds__(512, 8) void k_lvl4(
    const float* __restrict__ hprev, float* __restrict__ hnext,
    const int* __restrict__ offsets, const int* __restrict__ csr,
    const float* __restrict__ inv_cnt, const float* __restrict__ Wa,
    const float* __restrict__ We, int N) {
    level_body<32, 32, 32, 16, false>(hprev, hnext, offsets, csr, inv_cnt, Wa, We, N);
}

// Dense fold: g = h @ W, no relu. 32 nodes/block; thread -> float4 of cols.
template <int KIN, int DCO>
__global__ __launch_bounds__(256) void k_foldT(const float* __restrict__ hin,
                                               const float* __restrict__ W,
                                               float* __restrict__ gout, int N) {
    constexpr int PAD = KIN + 4;
    __shared__ float sW[KIN * DCO];
    __shared__ alignas(16) float sH[32 * PAD];
    const int t = threadIdx.x;
    const int base = blockIdx.x * 32;
    for (int i = t; i < KIN * DCO; i += 256) sW[i] = W[i];
    constexpr int RQ = KIN / 4;
    for (int idx = t; idx < 32 * RQ; idx += 256) {
        int row = idx / RQ, q = idx % RQ;
        int node = base + row;
        float4 v = (node < N) ? ((const float4*)hin)[(size_t)node * RQ + q]
                              : make_float4(0.f, 0.f, 0.f, 0.f);
        *(float4*)&sH[row * PAD + 4 * q] = v;
    }
    __syncthreads();
    constexpr int CQ = DCO / 4;
    constexpr int TILES = 32 * CQ;
#pragma unroll
    for (int j = 0; j < (TILES + 255) / 256; ++j) {
        int idx = t + j * 256;
        if (TILES % 256 == 0 || idx < TILES) {
            int row = idx / CQ, q = idx % CQ;
            int node = base + row;
            if (node < N) {
                float a0 = 0.f, a1 = 0.f, a2 = 0.f, a3 = 0.f;
#pragma unroll
                for (int k = 0; k < KIN; ++k) {
                    float mv = sH[row * PAD + k];
                    const float* w = &sW[k * DCO + 4 * q];
                    a0 += mv * w[0]; a1 += mv * w[1];
                    a2 += mv * w[2]; a3 += mv * w[3];
                }
                float4 r = make_float4(a0, a1, a2, a3);
                *(float4*)&gout[(size_t)node * DCO + 4 * q] = r;
            }
        }
    }
}

// Staged output projection (unchanged).
__global__ __launch_bounds__(256, 8) void k_out(const float* __restrict__ h,
                                                const int* __restrict__ nodes,
                                                const float* __restrict__ Wout,
                                                float* __restrict__ out, int B) {
    __shared__ alignas(16) float sH[32][36];
    __shared__ float sW[32 * 40];
    __shared__ int sIdx[32];
    const int t = threadIdx.x;
    const int base = blockIdx.x * 32;
    if (t < 32) sIdx[t] = (base + t < B) ? nodes[base + t] : 0;
    for (int i = t; i < 32 * 40; i += 256) sW[i] = Wout[i];
    __syncthreads();
    {
        int g = t >> 3, lg = t & 7;
        *(float4*)&sH[g][4 * lg] = ((const float4*)h)[(size_t)sIdx[g] * 8 + lg];
    }
    __syncthreads();
#pragma unroll
    for (int j = 0; j < 5; ++j) {
        int idx = t + j * 256;
        int n = idx / 40, c = idx % 40;
        if (base + n < B) {
            float s = 0.f;
#pragma unroll
            for (int k = 0; k < 32; ++k) s += sH[n][k] * sW[k * 40 + c];
            out[(size_t)(base + n) * 40 + c] = s;
        }
    }
}

extern "C" void kernel_launch(void* const* d_in, const int* in_sizes, int n_in,
                              void* d_out, int out_size, void* d_ws, size_t ws_size,
                              hipStream_t stream) {
    const float* raw  = (const float*)d_in[0];
    const int* nodes  = (const int*)d_in[1];
    const int* esrc   = (const int*)d_in[2];
    const int* edst   = (const int*)d_in[3];
    const float* Wa1 = (const float*)d_in[4];
    const float* Wa2 = (const float*)d_in[5];
    const float* Wa3 = (const float*)d_in[6];
    const float* Wa4 = (const float*)d_in[7];
    const float* We1 = (const float*)d_in[8];
    const float* We2 = (const float*)d_in[9];
    const float* We3 = (const float*)d_in[10];
    const float* We4 = (const float*)d_in[11];
    const float* Wout = (const float*)d_in[12];
    float* out = (float*)d_out;

    int N = in_sizes[1];   // 50000
    int E = in_sizes[2];   // 850000
    int B = N;
    int nbuck = (N + (1 << BSHIFT) - 1) >> BSHIFT;

    char* p = (char*)d_ws;
    auto alloc = [&](size_t bytes) -> char* {
        char* r = p;
        p += (bytes + 255) & ~(size_t)255;
        return r;
    };
    int*   deg     = (int*)alloc((size_t)N * 4);
    int*   offsets = (int*)alloc((size_t)(N + 1) * 4);
    float* inv_cnt = (float*)alloc((size_t)N * 4);
    int NB = (N + 1023) / 1024;
    int*   bsums   = (int*)alloc((size_t)NB * 4);
    int*   bcur    = (int*)alloc((size_t)MAXBUCK * 4);
    int*   csr     = (int*)alloc((size_t)E * 4);
    float* bufA    = (float*)alloc((size_t)N * 64 * 4);  // 12.8MB
    float* bufB    = (float*)alloc((size_t)N * 64 * 4);  // 12.8MB
    float* bufC    = (float*)alloc((size_t)N * 32 * 4);  // 6.4MB
    (void)ws_size; (void)n_in; (void)out_size;

    int2* staging = (int2*)bufA;   // overlay; dead before lvl2 writes bufA

    // Custom zero (replaces 44µs rocclr fill). N*4 bytes = N/4 int4s.
    int n4 = N / 4 + 1;
    k_zero<<<(n4 + 255) / 256, 256, 0, stream>>>((int4*)deg, N / 4);

    int eb256 = (E + 255) / 256;
    int eb512 = (E + 511) / 512;
    k_count<<<eb256, 256, 0, stream>>>(edst, deg, E);
    k_blocksum<<<NB, 256, 0, stream>>>(deg, bsums, N);
    k_scantop<<<1, 256, 0, stream>>>(bsums, NB);
    k_scanfinal<<<NB, 256, 0, stream>>>(deg, bsums, offsets, inv_cnt, N, E);
    k_binit<<<(nbuck + 255) / 256, 256, 0, stream>>>(offsets, bcur, nbuck, N);
    k_bucket<<<eb512, 512, 0, stream>>>(esrc, edst, bcur, staging, nbuck, E);
    k_place<<<nbuck, 512, 0, stream>>>(staging, offsets, csr, N, E);

    auto blocksFor = [](int n, int npb) {
        int b = (n + npb - 1) / npb;
        return b < 2048 ? b : 2048;
    };
    int fb = (N + 31) / 32;

    // Buffer timeline (r11, proven):
    float* h1 = bufB;
    float* g1 = bufC;
    float* h2 = bufA;
    float* g2 = bufB;
    float* h3 = bufA;
    float* g3 = bufC;
    float* h4 = bufB;

    k_lvl1<<<blocksFor(N, 128), 512, 0, stream>>>(raw, h1, offsets, csr, inv_cnt, Wa1, We1, N);
    k_foldT<32, 32><<<fb, 256, 0, stream>>>(h1, Wa2, g1, N);
    k_lvl2<<<blocksFor(N, 32), 512, 0, stream>>>(g1, h2, offsets, csr, inv_cnt, nullptr, We2, N);
    k_foldT<64, 64><<<fb, 256, 0, stream>>>(h2, Wa3, g2, N);
    k_lvl3<<<blocksFor(N, 16), 512, 0, stream>>>(g2, h3, offsets, csr, inv_cnt, nullptr, We3, N);
    k_foldT<64, 32><<<fb, 256, 0, stream>>>(h3, Wa4, g3, N);
    k_lvl4<<<blocksFor(N, 32), 512, 0, stream>>>(g3, h4, offsets, csr, inv_cnt, nullptr, We4, N);

    k_out<<<(B + 31) / 32, 256, 0, stream>>>(h4, nodes, Wout, out, B);
}